// Round 17
// baseline (38.193 us; speedup 1.0000x reference)
//
#include <hip/hip_runtime.h>

// ============================================================================
// PGALoss, analytically reduced:
//   per-point loss = sqrt(1 + d^2) + d,  d = NN distance
//   out = 0.5 * sum_dir clip((mean loss - 1)/2, 0, 1)
// d^2 = min_p(||p||^2 - 2 q.p) + ||q||^2   via bf16 hi/lo-split MFMA (R10)
//
// R17: PS=1 -> NN min is block-local. 256 blocks x 128 queries; each block
// streams the full 8192-point cloud through double-buffered LDS (8 chunks,
// 1 barrier/chunk). NO d2min table, NO per-query atomics, NO chunk counters.
// Per block: one f64 partial -> atomicExch slot -> last-of-256 (finalCnt,
// 512B memset) does a fixed-order tree sum (bitwise deterministic).
// ============================================================================

typedef short short8 __attribute__((ext_vector_type(8)));
typedef float f32x16 __attribute__((ext_vector_type(16)));

#define LDS_HALF 576             // 32 rows * 16B + 4 * 16B pad
#define LDS_TILE 1152            // two k-halves
#define CHUNK    1024            // points per LDS chunk
#define NCHUNK   8               // 8192 / 1024

// ws layout:
//   [0,4)       finalCnt u32   (memset 0x7f -> 0x7f7f7f7f)
//   [1024,3072) accP[256] u64  (double bits, atomicExch-written, no init)

__device__ __forceinline__ unsigned short bf16h(float f) {
    unsigned u = __float_as_uint(f);
    return (unsigned short)((u + 0x7fffu + ((u >> 16) & 1u)) >> 16);
}
__device__ __forceinline__ float bf16v(unsigned short h) {
    return __uint_as_float((unsigned)h << 16);
}

__global__ __launch_bounds__(256)
void fused_kernel(const float* __restrict__ src, const float* __restrict__ tgt,
                  unsigned* __restrict__ finalCnt,
                  unsigned long long* __restrict__ accP,
                  float* __restrict__ out, int N) {
    __shared__ __align__(16) unsigned char Alds[2][32 * LDS_TILE];  // 72 KB

    const int t   = threadIdx.x;
    const int l   = t & 63, w = t >> 6;
    const int nqc = N >> 7;                  // 64 query chunks (128 q each)
    const int task = blockIdx.x / nqc;       // 0..3 = s0,s1,t0,t1
    const int qc   = blockIdx.x % nqc;

    // ---- B-fragment (1 tile per wave: 32 queries) ----
    const int col = l & 31, h = l >> 5;
    const float* qRaw = (task < 2 ? src : tgt)
                        + (size_t)3 * (size_t)((task & 1) * N);
    const int qloc = qc * 128 + w * 32 + col;
    float q3[3];
    #pragma unroll
    for (int d = 0; d < 3; ++d) q3[d] = qRaw[3 * qloc + d];
    const float qq = q3[0]*q3[0] + q3[1]*q3[1] + q3[2]*q3[2];

    unsigned short B8[8];
    #pragma unroll
    for (int d = 0; d < 3; ++d) {
        const unsigned short qh = bf16h(q3[d]);
        B8[d] = qh;
        B8[4 + d] = (h == 0) ? bf16h(q3[d] - bf16v(qh)) : (unsigned short)0;
    }
    B8[3] = B8[7] = (h == 0) ? (unsigned short)0x3F80 : (unsigned short)0;
    const short8 b = *(const short8*)B8;

    // ---- point cloud base (other input, same batch) ----
    const int pcloud = task ^ 2;
    const float* pBase = (pcloud < 2 ? src : tgt)
                         + (size_t)3 * (size_t)((pcloud & 1) * N);

    // ---- chunk 0 prep ----
    {
        const float* pRaw = pBase;
        #pragma unroll
        for (int k = 0; k < 4; ++k) {
            const int j = t + k * 256;
            const float x = pRaw[3*j], y = pRaw[3*j+1], z = pRaw[3*j+2];
            const float pp = x*x + y*y + z*z;
            unsigned short A16[16];
            const float p3[3] = {x, y, z};
            #pragma unroll
            for (int d = 0; d < 3; ++d) {
                const float m2 = -2.0f * p3[d];
                const unsigned short th = bf16h(m2);
                A16[d] = th; A16[4+d] = th; A16[8+d] = bf16h(m2 - bf16v(th));
            }
            const unsigned short pph = bf16h(pp);
            A16[3] = pph; A16[7] = bf16h(pp - bf16v(pph)); A16[11] = 0;
            A16[12] = A16[13] = A16[14] = A16[15] = 0;
            const int tile = j >> 5, r = j & 31;
            unsigned char* base = Alds[0] + tile * LDS_TILE + r * 16 + (r >> 3) * 16;
            *(short8*)(base)            = *(const short8*)(A16);
            *(short8*)(base + LDS_HALF) = *(const short8*)(A16 + 8);
        }
    }
    __syncthreads();

    // ---- main loop: MFMA(chunk c) + prep(chunk c+1) per iteration ----
    const int lbase = h * LDS_HALF + col * 16 + (col >> 3) * 16;
    float best = 3.4e38f;
    const f32x16 zero = {};
    for (int c = 0; c < NCHUNK; ++c) {
        const unsigned char* buf = Alds[c & 1];
        #pragma unroll 4
        for (int i = 0; i < 32; ++i) {
            const short8 a = *(const short8*)(buf + i * LDS_TILE + lbase);
            f32x16 d0 = __builtin_amdgcn_mfma_f32_32x32x16_bf16(a, b, zero, 0, 0, 0);
            best = fminf(fminf(d0[0],  d0[1]),  best);
            best = fminf(fminf(d0[2],  d0[3]),  best);
            best = fminf(fminf(d0[4],  d0[5]),  best);
            best = fminf(fminf(d0[6],  d0[7]),  best);
            best = fminf(fminf(d0[8],  d0[9]),  best);
            best = fminf(fminf(d0[10], d0[11]), best);
            best = fminf(fminf(d0[12], d0[13]), best);
            best = fminf(fminf(d0[14], d0[15]), best);
        }
        if (c + 1 < NCHUNK) {
            const float* pRaw = pBase + (size_t)3 * (size_t)(c + 1) * CHUNK;
            unsigned char* nbuf = Alds[(c + 1) & 1];
            #pragma unroll
            for (int k = 0; k < 4; ++k) {
                const int j = t + k * 256;
                const float x = pRaw[3*j], y = pRaw[3*j+1], z = pRaw[3*j+2];
                const float pp = x*x + y*y + z*z;
                unsigned short A16[16];
                const float p3[3] = {x, y, z};
                #pragma unroll
                for (int d = 0; d < 3; ++d) {
                    const float m2 = -2.0f * p3[d];
                    const unsigned short th = bf16h(m2);
                    A16[d] = th; A16[4+d] = th; A16[8+d] = bf16h(m2 - bf16v(th));
                }
                const unsigned short pph = bf16h(pp);
                A16[3] = pph; A16[7] = bf16h(pp - bf16v(pph)); A16[11] = 0;
                A16[12] = A16[13] = A16[14] = A16[15] = 0;
                const int tile = j >> 5, r = j & 31;
                unsigned char* base = nbuf + tile * LDS_TILE + r * 16 + (r >> 3) * 16;
                *(short8*)(base)            = *(const short8*)(A16);
                *(short8*)(base + LDS_HALF) = *(const short8*)(A16 + 8);
            }
        }
        __syncthreads();
    }

    // ---- block-local finalize: f per query, fixed-order block sum ----
    best = fminf(best, __shfl_xor(best, 32));
    double fv = 0.0;
    if (l < 32) {
        const float d2 = fmaxf(best + qq, 0.0f);
        fv = (double)(sqrtf(1.0f + d2) + sqrtf(d2));
    }
    #pragma unroll
    for (int o = 32; o > 0; o >>= 1) fv += __shfl_down(fv, o);

    __shared__ double wsum[4];
    __shared__ int lastFinal;
    if (l == 0) wsum[w] = fv;
    __syncthreads();
    if (t == 0) {
        const double bs = (wsum[0] + wsum[1]) + (wsum[2] + wsum[3]);
        atomicExch(&accP[blockIdx.x], __double_as_longlong(bs));
        asm volatile("s_waitcnt vmcnt(0)" ::: "memory");   // exch at coherence
        lastFinal = (atomicAdd(finalCnt, 1u) == 0x7f7f7f7fu + 255u);
    }
    __syncthreads();
    if (!lastFinal) return;

    // ---- global finalize (exactly one block; fixed-order -> deterministic) ----
    const double pv = __longlong_as_double(
        (long long)atomicOr(&accP[t], 0ull));
    double a0 = (t < 128) ? pv : 0.0;       // blocks 0..127 = dir 0
    double a1 = (t < 128) ? 0.0 : pv;
    #pragma unroll
    for (int o = 32; o > 0; o >>= 1) {
        a0 += __shfl_down(a0, o);
        a1 += __shfl_down(a1, o);
    }
    __shared__ double fs0[4], fs1[4];
    if (l == 0) { fs0[w] = a0; fs1[w] = a1; }
    __syncthreads();
    if (t == 0) {
        const double s0 = (fs0[0] + fs0[1]) + (fs0[2] + fs0[3]);
        const double s1 = (fs1[0] + fs1[1]) + (fs1[2] + fs1[3]);
        const double inv = 1.0 / (double)(2 * N);
        double l0 = (s0 * inv - 1.0) * 0.5;
        double l1 = (s1 * inv - 1.0) * 0.5;
        l0 = l0 < 0.0 ? 0.0 : (l0 > 1.0 ? 1.0 : l0);
        l1 = l1 < 0.0 ? 0.0 : (l1 > 1.0 ? 1.0 : l1);
        out[0] = (float)(0.5 * (l0 + l1));
    }
}

extern "C" void kernel_launch(void* const* d_in, const int* in_sizes, int n_in,
                              void* d_out, int out_size, void* d_ws, size_t ws_size,
                              hipStream_t stream) {
    const float* src = (const float*)d_in[0];
    const float* tgt = (const float*)d_in[1];
    float* out = (float*)d_out;

    const int twoN = in_sizes[0] / 3;    // 16384 points per input
    const int N    = twoN / 2;           // 8192

    unsigned* finalCnt        = (unsigned*)d_ws;
    unsigned long long* accP  = (unsigned long long*)((char*)d_ws + 1024);

    hipMemsetAsync(d_ws, 0x7f, 512, stream);   // finalCnt known init

    const int blocks = 4 * (N >> 7);           // 256
    fused_kernel<<<blocks, 256, 0, stream>>>(src, tgt, finalCnt, accP, out, N);
}

// Round 18
// 24.796 us; speedup vs baseline: 1.5403x; 1.5403x over previous
//
#include <hip/hip_runtime.h>

// ============================================================================
// PGALoss, analytically reduced:
//   per-point loss = sqrt(1 + d^2) + d,  d = NN distance
//   out = 0.5 * sum_dir clip((mean loss - 1)/2, 0, 1)
// d^2 = min_p(||p||^2 - 2 q.p) + ||q||^2   via bf16 hi/lo-split MFMA
//
// R18: R16 skeleton (proven 24.8us) with the prep phase slimmed:
//   - truncation-based bf16 hi/lo split (lo limb exactly compensates hi
//     truncation; only dropped lo*lo term grows ~6e-5 rel) -> ~2x less VALU
//   - float4 point loads: 3 dwordx4 per thread (4 points) vs 12 scalar
// Everything else bit-identical to R16 (atomicMin chain, finalize, memset).
// ============================================================================

typedef short short8 __attribute__((ext_vector_type(8)));
typedef float f32x16 __attribute__((ext_vector_type(16)));

#define PPB      1024            // points per block
#define PS       8               // point chunks (N/PPB)
#define LDS_HALF 576             // 32 rows * 16B + 4 * 16B pad
#define LDS_TILE 1152            // two k-halves

// ws layout (memset 0x7f covers [0, 2048 + 4*QT)):
//   [0,512)     chunkCnt[128] u32   (init 0x7f7f7f7f)
//   [512,516)   finalCnt u32        (init 0x7f7f7f7f)
//   [1024,1536) accP[128] u32       (atomicExch-written float bits)
//   [2048,...)  d2min[QT] u32       (init 0x7f7f7f7f = +huge)

// truncation split: hi = bits>>16 (toward zero), lo = trunc(x - hi)
__device__ __forceinline__ unsigned short bf16t(float f) {
    return (unsigned short)(__float_as_uint(f) >> 16);
}
__device__ __forceinline__ float bf16v(unsigned short h) {
    return __uint_as_float((unsigned)h << 16);
}

__global__ __launch_bounds__(256, 4)
void fused_kernel(const float* __restrict__ src, const float* __restrict__ tgt,
                  unsigned* __restrict__ chunkCnt, unsigned* __restrict__ finalCnt,
                  unsigned* __restrict__ accP, unsigned* __restrict__ d2min,
                  float* __restrict__ out, int N) {
    __shared__ __align__(16) unsigned char Alds[32 * LDS_TILE];  // 36 KB

    const int t   = threadIdx.x;
    const int l   = t & 63, w = t >> 6;
    const int nqc = N >> 8;                  // 32 query chunks (256 q each)
    const int bpt = nqc * PS;                // 256 blocks per task
    const int task = blockIdx.x / bpt;       // 0..3 = s0,s1,t0,t1
    const int rem  = blockIdx.x % bpt;
    const int qc = rem / PS, pc = rem % PS;

    // ---- A-prep: 1024 points of cloud (task^2), chunk pc -> LDS ----
    // thread t preps points 4t..4t+3 via 3 float4 loads (48 contiguous bytes)
    const int pcloud = task ^ 2;
    const float* pRaw = (pcloud < 2 ? src : tgt)
                        + (size_t)3 * ((size_t)(pcloud & 1) * N + (size_t)pc * PPB);
    {
        const float4* p4 = (const float4*)pRaw + (size_t)3 * t;
        const float4 v0 = p4[0], v1 = p4[1], v2 = p4[2];
        float P[4][3] = {{v0.x, v0.y, v0.z}, {v0.w, v1.x, v1.y},
                         {v1.z, v1.w, v2.x}, {v2.y, v2.z, v2.w}};
        #pragma unroll
        for (int e = 0; e < 4; ++e) {
            const int j = 4 * t + e;
            const float x = P[e][0], y = P[e][1], z = P[e][2];
            const float pp = x*x + y*y + z*z;
            unsigned short A16[16];
            #pragma unroll
            for (int d = 0; d < 3; ++d) {
                const float m2 = -2.0f * P[e][d];
                const unsigned short th = bf16t(m2);
                A16[d] = th; A16[4+d] = th;
                A16[8+d] = bf16t(m2 - bf16v(th));
            }
            const unsigned short pph = bf16t(pp);
            A16[3] = pph; A16[7] = bf16t(pp - bf16v(pph)); A16[11] = 0;
            A16[12] = A16[13] = A16[14] = A16[15] = 0;
            const int tile = j >> 5, r = j & 31;
            unsigned char* base = Alds + tile * LDS_TILE + r * 16 + (r >> 3) * 16;
            *(short8*)(base)            = *(const short8*)(A16);
            *(short8*)(base + LDS_HALF) = *(const short8*)(A16 + 8);
        }
    }

    // ---- B-fragments in registers ----
    const int col = l & 31, h = l >> 5;
    const float* qRaw = (task < 2 ? src : tgt)
                        + (size_t)3 * (size_t)((task & 1) * N);
    const int qloc = qc * 256 + w * 64 + col;
    float qa[3], qb[3];
    #pragma unroll
    for (int d = 0; d < 3; ++d) {
        qa[d] = qRaw[3*qloc + d];
        qb[d] = qRaw[3*(qloc+32) + d];
    }
    const float qqa = qa[0]*qa[0] + qa[1]*qa[1] + qa[2]*qa[2];
    const float qqb = qb[0]*qb[0] + qb[1]*qb[1] + qb[2]*qb[2];

    unsigned short B0[8], B1[8];
    #pragma unroll
    for (int d = 0; d < 3; ++d) {
        const unsigned short ha = bf16t(qa[d]);
        const unsigned short hb = bf16t(qb[d]);
        B0[d] = ha; B1[d] = hb;
        B0[4+d] = (h == 0) ? bf16t(qa[d] - bf16v(ha)) : (unsigned short)0;
        B1[4+d] = (h == 0) ? bf16t(qb[d] - bf16v(hb)) : (unsigned short)0;
    }
    B0[3] = B0[7] = (h == 0) ? (unsigned short)0x3F80 : (unsigned short)0;
    B1[3] = B1[7] = B0[3];
    const short8 b0 = *(const short8*)B0;
    const short8 b1 = *(const short8*)B1;

    __syncthreads();

    // ---- MFMA loop over 32 tiles ----
    const int lbase = h * LDS_HALF + col * 16 + (col >> 3) * 16;
    float best0 = 3.4e38f, best1 = 3.4e38f;
    const f32x16 zero = {};
    #pragma unroll 4
    for (int i = 0; i < 32; ++i) {
        const short8 a = *(const short8*)(Alds + i * LDS_TILE + lbase);
        f32x16 d0 = __builtin_amdgcn_mfma_f32_32x32x16_bf16(a, b0, zero, 0, 0, 0);
        f32x16 d1 = __builtin_amdgcn_mfma_f32_32x32x16_bf16(a, b1, zero, 0, 0, 0);
        best0 = fminf(fminf(d0[0],  d0[1]),  best0);
        best0 = fminf(fminf(d0[2],  d0[3]),  best0);
        best0 = fminf(fminf(d0[4],  d0[5]),  best0);
        best0 = fminf(fminf(d0[6],  d0[7]),  best0);
        best0 = fminf(fminf(d0[8],  d0[9]),  best0);
        best0 = fminf(fminf(d0[10], d0[11]), best0);
        best0 = fminf(fminf(d0[12], d0[13]), best0);
        best0 = fminf(fminf(d0[14], d0[15]), best0);
        best1 = fminf(fminf(d1[0],  d1[1]),  best1);
        best1 = fminf(fminf(d1[2],  d1[3]),  best1);
        best1 = fminf(fminf(d1[4],  d1[5]),  best1);
        best1 = fminf(fminf(d1[6],  d1[7]),  best1);
        best1 = fminf(fminf(d1[8],  d1[9]),  best1);
        best1 = fminf(fminf(d1[10], d1[11]), best1);
        best1 = fminf(fminf(d1[12], d1[13]), best1);
        best1 = fminf(fminf(d1[14], d1[15]), best1);
    }

    // ---- merge + atomicMin (returns consumed -> complete before counter) ----
    best0 = fminf(best0, __shfl_xor(best0, 32));
    best1 = fminf(best1, __shfl_xor(best1, 32));
    const int qbase = task * N + qc * 256;
    if (l < 32) {
        const int q0 = qbase + w * 64 + l;
        unsigned o0 = atomicMin(&d2min[q0],
                                __float_as_uint(fmaxf(best0 + qqa, 0.0f)));
        unsigned o1 = atomicMin(&d2min[q0 + 32],
                                __float_as_uint(fmaxf(best1 + qqb, 0.0f)));
        asm volatile("" :: "v"(o0), "v"(o1));   // forces vmcnt drain
    }

    // ---- chunk-last detection ----
    __shared__ int lastChunk;
    __syncthreads();
    if (t == 0)
        lastChunk = (atomicAdd(&chunkCnt[task * nqc + qc], 1u)
                     == 0x7f7f7f7fu + (unsigned)PS - 1u);
    __syncthreads();
    if (!lastChunk) return;

    // ---- chunk finalize: 256 queries, atomic-coherent reads ----
    const float d2 = __uint_as_float(atomicOr(&d2min[qbase + t], 0u));
    double fv = (double)(sqrtf(1.0f + d2) + sqrtf(d2));
    #pragma unroll
    for (int o = 32; o > 0; o >>= 1) fv += __shfl_down(fv, o);
    __shared__ double wsum[4];
    __shared__ int lastFinal;
    if (l == 0) wsum[w] = fv;
    __syncthreads();
    if (t == 0) {
        const float csum = (float)(wsum[0] + wsum[1] + wsum[2] + wsum[3]);
        unsigned oldA = atomicExch(&accP[task * nqc + qc], __float_as_uint(csum));
        asm volatile("" :: "v"(oldA));          // exch complete at coherence
        lastFinal = (atomicAdd(finalCnt, 1u)
                     == 0x7f7f7f7fu + (unsigned)(4 * nqc) - 1u);
    }
    __syncthreads();
    if (!lastFinal) return;

    // ---- global finalize (exactly one block) ----
    __shared__ float pvals[128];
    const int ncid = 4 * nqc;                    // 128
    if (t < ncid) pvals[t] = __uint_as_float(atomicOr(&accP[t], 0u));
    __syncthreads();
    if (t == 0) {
        double s0 = 0.0, s1 = 0.0;
        for (int i = 0; i < ncid / 2; ++i)        s0 += (double)pvals[i];
        for (int i = ncid / 2; i < ncid; ++i)     s1 += (double)pvals[i];
        const double inv = 1.0 / (double)(2 * N);
        double l0 = (s0 * inv - 1.0) * 0.5;
        double l1 = (s1 * inv - 1.0) * 0.5;
        l0 = l0 < 0.0 ? 0.0 : (l0 > 1.0 ? 1.0 : l0);
        l1 = l1 < 0.0 ? 0.0 : (l1 > 1.0 ? 1.0 : l1);
        out[0] = (float)(0.5 * (l0 + l1));
    }
}

extern "C" void kernel_launch(void* const* d_in, const int* in_sizes, int n_in,
                              void* d_out, int out_size, void* d_ws, size_t ws_size,
                              hipStream_t stream) {
    const float* src = (const float*)d_in[0];
    const float* tgt = (const float*)d_in[1];
    float* out = (float*)d_out;

    const int twoN = in_sizes[0] / 3;    // 16384 points per input
    const int N    = twoN / 2;           // 8192
    const int QT   = 4 * N;              // 32768

    unsigned* chunkCnt = (unsigned*)d_ws;
    unsigned* finalCnt = (unsigned*)((char*)d_ws + 512);
    unsigned* accP     = (unsigned*)((char*)d_ws + 1024);
    unsigned* d2min    = (unsigned*)((char*)d_ws + 2048);

    // one memset node: counters AND d2min (+inf as uint) all 0x7f7f7f7f
    hipMemsetAsync(d_ws, 0x7f, 2048 + (size_t)QT * sizeof(unsigned), stream);

    const int blocks = 4 * (N >> 8) * PS;   // 1024
    fused_kernel<<<blocks, 256, 0, stream>>>(src, tgt, chunkCnt, finalCnt,
                                             accP, d2min, out, N);
}